// Round 5
// baseline (150.615 us; speedup 1.0000x reference)
//
#include <hip/hip_runtime.h>
#include <hip/hip_bf16.h>
#include <math.h>

// Problem constants
#define SEQ 4096
#define DM  1024
#define NIMU 72
#define NNOISE 12
#define NJ (NIMU*NNOISE)     // 864
#define TSTEPS 300
#define PLANE (NIMU*SEQ)     // 294912

// Fragment-linear layouts (16x16x32 bf16 MFMA operand granules):
//   granule(tile, ch) = 512 shorts; lane l holds 8 shorts at +l*8:
//     row = l&15 (m or n), k = ch*32 + (l>>4)*8 + 0..7
//   ch 0..31 = hi half (k 0..1023), ch 32..63 = lo half.
// A2f : 256 s_tiles x 64 ch x 512 shorts = 16.78 MB
// Btf : 56  j_tiles x 64 ch x 512 shorts =  3.67 MB (j_tiles 54,55 unwritten junk)
// pt  : 864 x 4096 f32 (planes >= 576 never written/read after R11 epilogue fold)
#define A2F_SHORTS ((size_t)256 * 64 * 512)
#define BTF_SHORTS ((size_t)56 * 64 * 512)

typedef __attribute__((ext_vector_type(8))) short bf16x8;
typedef __attribute__((ext_vector_type(4))) float f32x4;
typedef __attribute__((ext_vector_type(2))) float f32x2;

__device__ __forceinline__ float softplus_f(float x) {
    return fmaxf(x, 0.f) + log1pf(expf(-fabsf(x)));
}

// round-to-nearest-even bf16 split: x ~= hi + lo with |err| ~ 2^-16 * |x|
__device__ __forceinline__ void split_bf16(float x, short& hi, short& lo) {
    unsigned b = __float_as_uint(x);
    unsigned h = (b + 0x7FFFu + ((b >> 16) & 1u)) >> 16;
    float hf = __uint_as_float(h << 16);
    float r = x - hf;
    unsigned b2 = __float_as_uint(r);
    unsigned l2 = (b2 + 0x7FFFu + ((b2 >> 16) & 1u)) >> 16;
    hi = (short)h;
    lo = (short)l2;
}

// ---------------- 1. LayerNorm -> A2f (fragment-linear bf16 hi|lo) ----------------
// R12 counters (by construction): 256 blocks x 256 thr = 1 wave/SIMD -> latency-
// bound, ~12us vs 6us BW floor. R13: 1024-thread blocks (16 waves = 4/SIMD),
// 64 lanes per row (row = tid>>6 is wave-aligned -> full-wave shfl reduction).
__global__ __launch_bounds__(1024) void ln_kernel(const float* __restrict__ x,
                                                  const float* __restrict__ gamma,
                                                  const float* __restrict__ beta,
                                                  short* __restrict__ A2f) {
    const int s_tile = blockIdx.x;
    const int tid = threadIdx.x;
    const int mrow = tid >> 6;      // row within s_tile (wave-aligned)
    const int g    = tid & 63;
    const int row  = s_tile * 16 + mrow;
    const float4* xr = (const float4*)(x + (size_t)row * DM);

    float s = 0.f, sq = 0.f;
    #pragma unroll
    for (int i = 0; i < 4; ++i) {
        float4 v = xr[g + 64 * i];
        s  += v.x + v.y + v.z + v.w;
        sq += v.x*v.x + v.y*v.y + v.z*v.z + v.w*v.w;
    }
    #pragma unroll
    for (int off = 1; off < 64; off <<= 1) {
        s  += __shfl_xor(s, off);
        sq += __shfl_xor(sq, off);
    }
    const float mean = s * (1.f / DM);
    const float var  = sq * (1.f / DM) - mean * mean;
    const float rstd = rsqrtf(fmaxf(var, 0.f) + 1e-5f);

    #pragma unroll
    for (int i = 0; i < 4; ++i) {
        const int c4 = g + 64 * i;           // float4 column 0..255
        float4 v = xr[c4];
        float4 gm = ((const float4*)gamma)[c4];
        float4 bt = ((const float4*)beta)[c4];
        float o[4];
        o[0] = (v.x - mean) * rstd * gm.x + bt.x;
        o[1] = (v.y - mean) * rstd * gm.y + bt.y;
        o[2] = (v.z - mean) * rstd * gm.z + bt.z;
        o[3] = (v.w - mean) * rstd * gm.w + bt.w;
        short4 hv, lv;
        split_bf16(o[0], hv.x, lv.x);
        split_bf16(o[1], hv.y, lv.y);
        split_bf16(o[2], hv.z, lv.z);
        split_bf16(o[3], hv.w, lv.w);
        const int ch = c4 >> 3;
        const size_t base = ((size_t)s_tile * 64 + ch) * 512
                          + mrow * 8 + ((c4 >> 1) & 3) * 128 + (c4 & 1) * 4;
        *(short4*)(A2f + base)             = hv;   // hi: ch
        *(short4*)(A2f + base + 32 * 512)  = lv;   // lo: ch+32
    }
}

// ---------------- 2a. W -> Btf (transpose + split, fragment-linear) ----------------
__global__ __launch_bounds__(256) void wprep_kernel(const float* __restrict__ W,
                                                    short* __restrict__ Btf) {
    __shared__ float T[32][33];
    const int k0 = blockIdx.x * 32, j0 = blockIdx.y * 32;
    const int t = threadIdx.x;
    {
        const int r = t >> 3, c4 = (t & 7) * 4;
        float4 v = *(const float4*)(W + (size_t)(k0 + r) * NJ + j0 + c4);
        T[r][c4 + 0] = v.x; T[r][c4 + 1] = v.y; T[r][c4 + 2] = v.z; T[r][c4 + 3] = v.w;
    }
    __syncthreads();
    if (t < 128) {
        const int gq = t >> 6;          // which 16-j group
        const int l  = t & 63;
        const int n = l & 15, c = l >> 4;
        const int jt = blockIdx.y * 2 + gq;       // j_tile
        bf16x8 hv, lv;
        #pragma unroll
        for (int o = 0; o < 8; ++o) {
            short h, lo_;
            split_bf16(T[c * 8 + o][gq * 16 + n], h, lo_);
            hv[o] = h; lv[o] = lo_;
        }
        short* dh = Btf + ((size_t)jt * 64 + blockIdx.x) * 512 + l * 8;
        *(bf16x8*)dh = hv;
        *(bf16x8*)(dh + (size_t)32 * 512) = lv;   // lo chunk = ch+32
    }
}

// ---------------- 2b. Barrier-free MFMA GEMM + fused tail epilogue ----------------
// R12: 224 blocks caps occupancy at 1 block/CU = 2 waves/SIMD (32 CUs idle).
// R13: block tile 64x128 -> 448 blocks x 512 thr, wave tile 2m x 2j (8 loads /
// 12 MFMA per k-step). __launch_bounds__(512,4) caps VGPR at 128 so 2 blocks/CU
// co-reside -> ~4 waves/SIMD. XCD chunking: xcd c = bid&7 owns bx in [8c,8c+8) x
// all 7 by (A-set 2MB + Btf 3.7MB ~ L2-resident). Fused tail epilogue unchanged.
__global__ __launch_bounds__(512, 4) void gemm_kernel(const short* __restrict__ A2f,
                                                      const short* __restrict__ Btf,
                                                      const float* __restrict__ bias,
                                                      float* __restrict__ pt,
                                                      float* __restrict__ out) {
    const int bid = blockIdx.x;
    const int c = bid & 7, u = bid >> 3;       // c = XCD, u in 0..55
    const int bxi = u / 7;
    const int by = u - bxi * 7;
    const int bx = c * 8 + bxi;                // 0..63 (64-row m-block)
    const int l = threadIdx.x & 63, w = threadIdx.x >> 6;   // w in 0..7
    const int wm = w & 1, wj = w >> 1;
    const int st0 = bx * 4 + wm * 2;           // wave's m-tile base (2 tiles)
    const int jt0 = by * 8 + wj * 2;           // wave's n-tile base (2 tiles)
    const short* aB = A2f + (size_t)st0 * (64 * 512) + l * 8;
    const short* bB = Btf + (size_t)jt0 * (64 * 512) + l * 8;

    f32x4 acc[2][2] = {};
    bf16x8 ah[2][2], al[2][2], bh[2][2], bl[2][2];

    auto ldstep = [&](int slot, int i) {
        #pragma unroll
        for (int t = 0; t < 2; ++t) {
            ah[slot][t] = *(const bf16x8*)(aB + ((size_t)t * 64 + i) * 512);
            al[slot][t] = *(const bf16x8*)(aB + ((size_t)t * 64 + 32 + i) * 512);
            bh[slot][t] = *(const bf16x8*)(bB + ((size_t)t * 64 + i) * 512);
            bl[slot][t] = *(const bf16x8*)(bB + ((size_t)t * 64 + 32 + i) * 512);
        }
    };

    ldstep(0, 0);
    #pragma unroll 2
    for (int i = 0; i < 32; ++i) {
        const int cur = i & 1;
        if (i + 1 < 32) ldstep(cur ^ 1, i + 1);   // loads in flight during MFMA
        #pragma unroll
        for (int mi = 0; mi < 2; ++mi)
            #pragma unroll
            for (int ni = 0; ni < 2; ++ni)
                acc[mi][ni] = __builtin_amdgcn_mfma_f32_16x16x32_bf16(
                    ah[cur][mi], bh[cur][ni], acc[mi][ni], 0, 0, 0);
        #pragma unroll
        for (int mi = 0; mi < 2; ++mi)
            #pragma unroll
            for (int ni = 0; ni < 2; ++ni)
                acc[mi][ni] = __builtin_amdgcn_mfma_f32_16x16x32_bf16(
                    ah[cur][mi], bl[cur][ni], acc[mi][ni], 0, 0, 0);
        #pragma unroll
        for (int mi = 0; mi < 2; ++mi)
            #pragma unroll
            for (int ni = 0; ni < 2; ++ni)
                acc[mi][ni] = __builtin_amdgcn_mfma_f32_16x16x32_bf16(
                    al[cur][mi], bh[cur][ni], acc[mi][ni], 0, 0, 0);
    }

    // epilogue: C/D layout col=lane&15 (j-within-tile), row=(lane>>4)*4+reg (s)
    const int srow = (l >> 4) * 4;
    const int jcol = l & 15;
    #pragma unroll
    for (int ni = 0; ni < 2; ++ni) {
        const int jt = jt0 + ni;
        const int j = jt * 16 + jcol;
        if (j < NJ) {
            const float bj = bias[j];
            if (jt < 36) {                       // noise planes 0..7 -> pt (spring input)
                #pragma unroll
                for (int mi = 0; mi < 2; ++mi) {
                    f32x4 v = acc[mi][ni];
                    v[0] += bj; v[1] += bj; v[2] += bj; v[3] += bj;
                    *(f32x4*)(pt + (size_t)j * SEQ + (st0 + mi) * 16 + srow) = v;
                }
            } else {                             // noise planes 8..11 -> out directly
                const int noise = j / 72;        // 8..11
                const int imu = j - noise * 72;
                float* dst = out + (size_t)(noise - 7) * PLANE + (size_t)imu * SEQ;
                const bool sp = (noise & 1);
                #pragma unroll
                for (int mi = 0; mi < 2; ++mi) {
                    f32x4 v = acc[mi][ni];
                    v[0] += bj; v[1] += bj; v[2] += bj; v[3] += bj;
                    if (sp) {
                        v[0] = softplus_f(v[0]); v[1] = softplus_f(v[1]);
                        v[2] = softplus_f(v[2]); v[3] = softplus_f(v[3]);
                    }
                    *(f32x4*)(dst + (st0 + mi) * 16 + srow) = v;
                }
            }
        }
    }
}

// ---------------- 3. Spring recurrence + wave-private LDS-window scatter ----------------
// R11: 3-parity buffers w3[j%3]. A barrier-group = 3 macro-steps; each buffer is
// RMW'd at exactly one step index per group (plus the B-stream +150 slot: lane
// distance 150 > 63 -> race-free), so all 6 reads issue together -> ONE lgkm wait
// per 3 macro-steps (50 waits). Cross-group RAW (lane l reads what lane l+3 wrote
// last group) pinned by one memory-clobber per group + in-order LDS pipe.
// DS floor ~1 DS-op per contribution (read2/write2 fuse A+B pairs) ~ 13us/CU-share;
// no cheap lever left here -- unchanged in R13.
__global__ __launch_bounds__(256) void spring_kernel(const float* __restrict__ pt,
                                                     float* __restrict__ kin) {
    __shared__ float w3[3][4 * 368];           // 363 used per wave per parity
    const int tid  = threadIdx.x;
    const int lane = tid & 63;
    const int wid  = tid >> 6;
    const int s0   = blockIdx.x * 256;
    const int imu  = blockIdx.y;
    const int s    = s0 + (wid << 6) + lane;

    // zero own windows (wave-private: no barrier needed before main loop)
    #pragma unroll
    for (int b = 0; b < 3; ++b)
        #pragma unroll
        for (int i = 0; i < 6; ++i) {
            const int idx = lane + i * 64;
            if (idx < 363) w3[b][wid * 368 + idx] = 0.f;
        }

    const int base = imu * SEQ + s;
    const float p0  = pt[(size_t)0 * PLANE + base];
    const float p1  = pt[(size_t)1 * PLANE + base];
    const float p2  = pt[(size_t)2 * PLANE + base];
    const float p3  = pt[(size_t)3 * PLANE + base];
    const float c1  = pt[(size_t)4 * PLANE + base];
    const float c2  = pt[(size_t)5 * PLANE + base];
    const float ph1 = pt[(size_t)6 * PLANE + base];
    const float ph2 = pt[(size_t)7 * PLANE + base];

    float dd = softplus_f(p1);
    float kk = dd * dd * 0.25f + softplus_f(p0);
    float om1 = 0.5f * sqrtf(fmaxf(4.f * kk - dd * dd, 0.f));
    float dt = softplus_f(p3);
    float kt = dt * dt * 0.25f + softplus_f(p2);
    float om2 = 0.5f * sqrtf(fmaxf(4.f * kt - dt * dt, 0.f));
    float e1 = expf(-0.5f * dd), e2 = expf(-0.5f * dt);
    float sn, cs, sn2, cs2;
    sincosf(om1, &sn, &cs);
    sincosf(om2, &sn2, &cs2);
    f32x2 Rr = {e1 * cs, e2 * cs2};          // per-step rotation (packed: osc1, osc2)
    f32x2 Ri = {e1 * sn, e2 * sn2};
    sincosf(ph1, &sn, &cs);
    sincosf(ph2, &sn2, &cs2);
    f32x2 zr = {c1 * cs, c2 * cs2};          // stream A state (t = 0)
    f32x2 zi = {c1 * sn, c2 * sn2};

    // stream B state: z * R^150 (exp-by-squaring)
    f32x2 zrB, ziB;
    {
        f32x2 prr = Rr, pri = Ri;
        f32x2 qr = {1.f, 1.f}, qi = {0.f, 0.f};
        int e = 150;
        while (e) {
            if (e & 1) {
                f32x2 nr = qr * prr - qi * pri;
                qi = qr * pri + qi * prr;
                qr = nr;
            }
            f32x2 nr = prr * prr - pri * pri;
            pri = 2.f * prr * pri;
            prr = nr;
            e >>= 1;
        }
        f32x2 nr = zr * qr - zi * qi;
        ziB = zr * qi + zi * qr;
        zrB = nr;
    }

    float* q0 = &w3[0][wid * 368 + lane];
    float* q1 = &w3[1][wid * 368 + lane];
    float* q2 = &w3[2][wid * 368 + lane];

    #pragma unroll 1
    for (int j = 0; j < 150; j += 3) {
        // values for macro-steps j, j+1, j+2 on both streams
        float vA0 = zi.x + zi.y;
        { f32x2 nr = zr * Rr - zi * Ri; zi = zr * Ri + zi * Rr; zr = nr; }
        float vA1 = zi.x + zi.y;
        { f32x2 nr = zr * Rr - zi * Ri; zi = zr * Ri + zi * Rr; zr = nr; }
        float vA2 = zi.x + zi.y;
        { f32x2 nr = zr * Rr - zi * Ri; zi = zr * Ri + zi * Rr; zr = nr; }
        float vB0 = ziB.x + ziB.y;
        { f32x2 nr = zrB * Rr - ziB * Ri; ziB = zrB * Ri + ziB * Rr; zrB = nr; }
        float vB1 = ziB.x + ziB.y;
        { f32x2 nr = zrB * Rr - ziB * Ri; ziB = zrB * Ri + ziB * Rr; zrB = nr; }
        float vB2 = ziB.x + ziB.y;
        { f32x2 nr = zrB * Rr - ziB * Ri; ziB = zrB * Ri + ziB * Rr; zrB = nr; }

        // all 6 reads issue together -> single lgkm wait per group
        const float a0 = q0[j],     b0 = q0[j + 150];
        const float a1 = q1[j + 1], b1 = q1[j + 151];
        const float a2 = q2[j + 2], b2 = q2[j + 152];
        q0[j]       = a0 + vA0;  q0[j + 150] = b0 + vB0;
        q1[j + 1]   = a1 + vA1;  q1[j + 151] = b1 + vB1;
        q2[j + 2]   = a2 + vA2;  q2[j + 152] = b2 + vB2;
        __asm__ volatile("" ::: "memory");   // pin group order (cross-lane RAW, dist 3)
    }

    __syncthreads();
    // merge 3 parities x 4 wave windows + masked global flush
    for (int i = tid; i < 555; i += 256) {
        float sum = 0.f;
        #pragma unroll
        for (int w = 0; w < 4; ++w) {
            const int idx = i - (w << 6);
            if (idx >= 0 && idx < 363) {
                const int o = w * 368 + idx;
                sum += w3[0][o] + w3[1][o] + w3[2][o];
            }
        }
        const int pos = s0 + i;
        if (pos < SEQ) {
            (void)__hip_atomic_fetch_add(&kin[(size_t)imu * SEQ + pos], sum,
                                         __ATOMIC_RELAXED, __HIP_MEMORY_SCOPE_AGENT);
        }
    }
}

extern "C" void kernel_launch(void* const* d_in, const int* in_sizes, int n_in,
                              void* d_out, int out_size, void* d_ws, size_t ws_size,
                              hipStream_t stream) {
    const float* hs    = (const float*)d_in[0];
    const float* gamma = (const float*)d_in[1];
    const float* beta  = (const float*)d_in[2];
    const float* W     = (const float*)d_in[3];
    const float* b     = (const float*)d_in[4];
    float* out = (float*)d_out;

    short* A2f = (short*)d_ws;                        // 16.78 MB
    short* Btf = A2f + A2F_SHORTS;                    //  3.67 MB
    float* pt  = (float*)(Btf + BTF_SHORTS);          // 14.16 MB (planes 0..7 used)

    hipMemsetAsync(out, 0, (size_t)PLANE * sizeof(float), stream);

    ln_kernel<<<SEQ / 16, 1024, 0, stream>>>(hs, gamma, beta, A2f);
    wprep_kernel<<<dim3(DM / 32, NJ / 32), 256, 0, stream>>>(W, Btf);
    gemm_kernel<<<448, 512, 0, stream>>>(A2f, Btf, b, pt, out);
    spring_kernel<<<dim3(SEQ / 256, NIMU), 256, 0, stream>>>(pt, out);
}

// Round 6
// 143.992 us; speedup vs baseline: 1.0460x; 1.0460x over previous
//
#include <hip/hip_runtime.h>
#include <hip/hip_bf16.h>
#include <math.h>

// Problem constants
#define SEQ 4096
#define DM  1024
#define NIMU 72
#define NNOISE 12
#define NJ (NIMU*NNOISE)     // 864
#define TSTEPS 300
#define PLANE (NIMU*SEQ)     // 294912

// R14 fragment-linear layouts (32x32x16 bf16 MFMA granules):
//   granule(tile, ch) = 512 shorts (1KB); lane l holds 8 shorts at +l*8:
//     row/col = l&31, k = ch*16 + (l>>5)*8 + 0..7
//   ch 0..63 = hi half (k 0..1023), ch 64..127 = lo half.
// A2f : 128 s_tiles x 128 ch x 512 shorts = 16.78 MB
// Btf : 28  j_tiles x 128 ch x 512 shorts =  3.67 MB (tile 27 = pad, never written)
// ptA/ptB : 12 x PLANE f32 split-K partials (14.16 MB each)
#define A2F_SHORTS ((size_t)128 * 128 * 512)
#define BTF_SHORTS ((size_t)28 * 128 * 512)

typedef __attribute__((ext_vector_type(8))) short bf16x8;
typedef __attribute__((ext_vector_type(16))) float f32x16;
typedef __attribute__((ext_vector_type(4))) float f32x4;
typedef __attribute__((ext_vector_type(2))) float f32x2;

__device__ __forceinline__ float softplus_f(float x) {
    return fmaxf(x, 0.f) + log1pf(expf(-fabsf(x)));
}

// round-to-nearest-even bf16 split: x ~= hi + lo with |err| ~ 2^-16 * |x|
__device__ __forceinline__ void split_bf16(float x, short& hi, short& lo) {
    unsigned b = __float_as_uint(x);
    unsigned h = (b + 0x7FFFu + ((b >> 16) & 1u)) >> 16;
    float hf = __uint_as_float(h << 16);
    float r = x - hf;
    unsigned b2 = __float_as_uint(r);
    unsigned l2 = (b2 + 0x7FFFu + ((b2 >> 16) & 1u)) >> 16;
    hi = (short)h;
    lo = (short)l2;
}

// ---------------- 1. LayerNorm -> A2f (32-row granules, bf16 hi|lo) ----------------
// 512 thr = 8 waves (2 rows/wave, 32 lanes/row), grid 256 -> 2 waves/SIMD chip-wide.
__global__ __launch_bounds__(512) void ln_kernel(const float* __restrict__ x,
                                                 const float* __restrict__ gamma,
                                                 const float* __restrict__ beta,
                                                 short* __restrict__ A2f) {
    const int tid = threadIdx.x;
    const int row = blockIdx.x * 16 + (tid >> 5);
    const int c   = tid & 31;
    const float4* xr = (const float4*)(x + (size_t)row * DM);

    float s = 0.f, sq = 0.f;
    #pragma unroll
    for (int i = 0; i < 8; ++i) {
        float4 v = xr[c + 32 * i];
        s  += v.x + v.y + v.z + v.w;
        sq += v.x*v.x + v.y*v.y + v.z*v.z + v.w*v.w;
    }
    #pragma unroll
    for (int off = 1; off < 32; off <<= 1) {     // 32-lane row groups within wave
        s  += __shfl_xor(s, off);
        sq += __shfl_xor(sq, off);
    }
    const float mean = s * (1.f / DM);
    const float var  = sq * (1.f / DM) - mean * mean;
    const float rstd = rsqrtf(fmaxf(var, 0.f) + 1e-5f);

    const int s_tile = row >> 5, r = row & 31;
    #pragma unroll
    for (int i = 0; i < 8; ++i) {
        const int c4 = c + 32 * i;               // float4 column 0..255, k = 4*c4..+3
        float4 v  = xr[c4];
        float4 gm = ((const float4*)gamma)[c4];
        float4 bt = ((const float4*)beta)[c4];
        float o[4];
        o[0] = (v.x - mean) * rstd * gm.x + bt.x;
        o[1] = (v.y - mean) * rstd * gm.y + bt.y;
        o[2] = (v.z - mean) * rstd * gm.z + bt.z;
        o[3] = (v.w - mean) * rstd * gm.w + bt.w;
        short4 hv, lv;
        split_bf16(o[0], hv.x, lv.x);
        split_bf16(o[1], hv.y, lv.y);
        split_bf16(o[2], hv.z, lv.z);
        split_bf16(o[3], hv.w, lv.w);
        const int ch = c4 >> 2;                  // 16-k chunk
        const int g  = (c4 >> 1) & 1;            // 8-k group within chunk
        const int o4 = (c4 & 1) * 4;             // short offset within group
        const size_t base = ((size_t)s_tile * 128 + ch) * 512 + (g * 32 + r) * 8 + o4;
        *(short4*)(A2f + base)                    = hv;   // hi: ch
        *(short4*)(A2f + base + (size_t)64 * 512) = lv;   // lo: ch+64
    }
}

// ---------------- 2a. W -> Btf (transpose + split, 32-col granules) ----------------
__global__ __launch_bounds__(256) void wprep_kernel(const float* __restrict__ W,
                                                    short* __restrict__ Btf) {
    __shared__ float T[32][33];
    const int k0 = blockIdx.x * 32, j0 = blockIdx.y * 32;
    const int t = threadIdx.x;
    {
        const int r = t >> 3, c4 = (t & 7) * 4;
        float4 v = *(const float4*)(W + (size_t)(k0 + r) * NJ + j0 + c4);
        T[r][c4 + 0] = v.x; T[r][c4 + 1] = v.y; T[r][c4 + 2] = v.z; T[r][c4 + 3] = v.w;
    }
    __syncthreads();
    if (t < 128) {
        const int q = t >> 6;                    // which 16-k chunk of the 32
        const int l = t & 63;
        const int n = l & 31, g = l >> 5;
        const int jt = blockIdx.y;               // j_tile (32 cols)
        const int ch = blockIdx.x * 2 + q;
        bf16x8 hv, lv;
        #pragma unroll
        for (int o = 0; o < 8; ++o) {
            short h, lo_;
            split_bf16(T[q * 16 + g * 8 + o][n], h, lo_);
            hv[o] = h; lv[o] = lo_;
        }
        short* dh = Btf + ((size_t)jt * 128 + ch) * 512 + l * 8;
        *(bf16x8*)dh = hv;
        *(bf16x8*)(dh + (size_t)64 * 512) = lv;  // lo chunk = ch+64
    }
}

// ---------------- 2b. Barrier-free MFMA GEMM, 32x32x16, split-K=2 ----------------
// R13 post-mortem: L2-BW-bound (917 MB vector-load traffic at ~22 TB/s ~ 42us;
// MfmaUtil 17% passenger). R14: 32x32x16 granules double FLOP/byte (same operand
// bytes per MFMA, 2x FLOP) -> 459 MB; split-K=2 restores the block count (448)
// that R12 proved necessary for >=2 waves/SIMD. Wave tile 64x64 (2x2 of 32x32),
// block 128x128 (4 waves), K=512/half. XCD chunking: c=bid&7 owns 4 bx panels x
// 7 by x 1 kh -> per-XCD set (4x256KB A + 1.8MB B-half) L2-resident.
// Both halves write raw partials (bias in half 0); combine in spring/tail.
__global__ __launch_bounds__(256, 2) void gemm_kernel(const short* __restrict__ A2f,
                                                      const short* __restrict__ Btf,
                                                      const float* __restrict__ bias,
                                                      float* __restrict__ ptA,
                                                      float* __restrict__ ptB) {
    const int bid = blockIdx.x;
    const int c = bid & 7, u = bid >> 3;         // c = XCD, u 0..55
    const int kh = u / 28, v = u - kh * 28;      // kh = K-half
    const int bxi = v / 7, by = v - bxi * 7;     // bxi 0..3, by 0..6
    const int bx = c * 4 + bxi;                  // 0..31
    const int l = threadIdx.x & 63, w = threadIdx.x >> 6;
    const int mt0 = bx * 4 + (w & 1) * 2;        // wave's m-tile base (32-row tiles)
    const int jt0 = by * 4 + (w >> 1) * 2;       // wave's j-tile base (32-col tiles)
    const int ch0 = kh * 32;                     // 16-k chunks 0..63; half = 32 chunks
    const short* aB = A2f + (size_t)mt0 * (128 * 512) + l * 8;
    const short* bB = Btf + (size_t)jt0 * (128 * 512) + l * 8;

    f32x16 acc[2][2] = {};
    bf16x8 ah[2][2], al[2][2], bh[2][2], bl[2][2];

    auto ldstep = [&](int slot, int i) {
        const size_t chh = ch0 + i, chl = chh + 64;
        #pragma unroll
        for (int t = 0; t < 2; ++t) {
            ah[slot][t] = *(const bf16x8*)(aB + ((size_t)t * 128 + chh) * 512);
            al[slot][t] = *(const bf16x8*)(aB + ((size_t)t * 128 + chl) * 512);
            bh[slot][t] = *(const bf16x8*)(bB + ((size_t)t * 128 + chh) * 512);
            bl[slot][t] = *(const bf16x8*)(bB + ((size_t)t * 128 + chl) * 512);
        }
    };

    ldstep(0, 0);
    #pragma unroll 2
    for (int i = 0; i < 32; ++i) {
        const int cur = i & 1;
        if (i + 1 < 32) ldstep(cur ^ 1, i + 1);   // loads in flight during MFMA
        #pragma unroll
        for (int mi = 0; mi < 2; ++mi)
            #pragma unroll
            for (int ni = 0; ni < 2; ++ni)
                acc[mi][ni] = __builtin_amdgcn_mfma_f32_32x32x16_bf16(
                    ah[cur][mi], bh[cur][ni], acc[mi][ni], 0, 0, 0);
        #pragma unroll
        for (int mi = 0; mi < 2; ++mi)
            #pragma unroll
            for (int ni = 0; ni < 2; ++ni)
                acc[mi][ni] = __builtin_amdgcn_mfma_f32_32x32x16_bf16(
                    ah[cur][mi], bl[cur][ni], acc[mi][ni], 0, 0, 0);
        #pragma unroll
        for (int mi = 0; mi < 2; ++mi)
            #pragma unroll
            for (int ni = 0; ni < 2; ++ni)
                acc[mi][ni] = __builtin_amdgcn_mfma_f32_32x32x16_bf16(
                    al[cur][mi], bh[cur][ni], acc[mi][ni], 0, 0, 0);
    }

    // epilogue: 32x32 C/D layout col=lane&31 (j), row=(reg&3)+8*(reg>>2)+4*(lane>>5)
    float* ptH = kh ? ptB : ptA;
    const int jn = l & 31, hi5 = l >> 5;
    #pragma unroll
    for (int ni = 0; ni < 2; ++ni) {
        const int jt = jt0 + ni;
        if (jt < 27) {                            // tile 27 = pad, fully masked
            const int j = jt * 32 + jn;
            const float bj = (kh == 0) ? bias[j] : 0.f;
            #pragma unroll
            for (int mi = 0; mi < 2; ++mi) {
                #pragma unroll
                for (int q = 0; q < 4; ++q) {     // reg quad q -> rows q*8+hi5*4+0..3
                    f32x4 o;
                    o[0] = acc[mi][ni][q * 4 + 0] + bj;
                    o[1] = acc[mi][ni][q * 4 + 1] + bj;
                    o[2] = acc[mi][ni][q * 4 + 2] + bj;
                    o[3] = acc[mi][ni][q * 4 + 3] + bj;
                    const int s = (mt0 + mi) * 32 + q * 8 + hi5 * 4;
                    *(f32x4*)(ptH + (size_t)j * SEQ + s) = o;
                }
            }
        }
    }
}

// ---------------- 3. Spring recurrence + wave-private LDS-window scatter ----------------
// R11 structure unchanged (3-parity buffers, 1 lgkm wait per 3 macro-steps).
// R14: inputs are split-K partial sums ptA+ptB.
__global__ __launch_bounds__(256) void spring_kernel(const float* __restrict__ ptA,
                                                     const float* __restrict__ ptB,
                                                     float* __restrict__ kin) {
    __shared__ float w3[3][4 * 368];           // 363 used per wave per parity
    const int tid  = threadIdx.x;
    const int lane = tid & 63;
    const int wid  = tid >> 6;
    const int s0   = blockIdx.x * 256;
    const int imu  = blockIdx.y;
    const int s    = s0 + (wid << 6) + lane;

    // zero own windows (wave-private: no barrier needed before main loop)
    #pragma unroll
    for (int b = 0; b < 3; ++b)
        #pragma unroll
        for (int i = 0; i < 6; ++i) {
            const int idx = lane + i * 64;
            if (idx < 363) w3[b][wid * 368 + idx] = 0.f;
        }

    const int base = imu * SEQ + s;
    const float p0  = ptA[(size_t)0 * PLANE + base] + ptB[(size_t)0 * PLANE + base];
    const float p1  = ptA[(size_t)1 * PLANE + base] + ptB[(size_t)1 * PLANE + base];
    const float p2  = ptA[(size_t)2 * PLANE + base] + ptB[(size_t)2 * PLANE + base];
    const float p3  = ptA[(size_t)3 * PLANE + base] + ptB[(size_t)3 * PLANE + base];
    const float c1  = ptA[(size_t)4 * PLANE + base] + ptB[(size_t)4 * PLANE + base];
    const float c2  = ptA[(size_t)5 * PLANE + base] + ptB[(size_t)5 * PLANE + base];
    const float ph1 = ptA[(size_t)6 * PLANE + base] + ptB[(size_t)6 * PLANE + base];
    const float ph2 = ptA[(size_t)7 * PLANE + base] + ptB[(size_t)7 * PLANE + base];

    float dd = softplus_f(p1);
    float kk = dd * dd * 0.25f + softplus_f(p0);
    float om1 = 0.5f * sqrtf(fmaxf(4.f * kk - dd * dd, 0.f));
    float dt = softplus_f(p3);
    float kt = dt * dt * 0.25f + softplus_f(p2);
    float om2 = 0.5f * sqrtf(fmaxf(4.f * kt - dt * dt, 0.f));
    float e1 = expf(-0.5f * dd), e2 = expf(-0.5f * dt);
    float sn, cs, sn2, cs2;
    sincosf(om1, &sn, &cs);
    sincosf(om2, &sn2, &cs2);
    f32x2 Rr = {e1 * cs, e2 * cs2};          // per-step rotation (packed: osc1, osc2)
    f32x2 Ri = {e1 * sn, e2 * sn2};
    sincosf(ph1, &sn, &cs);
    sincosf(ph2, &sn2, &cs2);
    f32x2 zr = {c1 * cs, c2 * cs2};          // stream A state (t = 0)
    f32x2 zi = {c1 * sn, c2 * sn2};

    // stream B state: z * R^150 (exp-by-squaring)
    f32x2 zrB, ziB;
    {
        f32x2 prr = Rr, pri = Ri;
        f32x2 qr = {1.f, 1.f}, qi = {0.f, 0.f};
        int e = 150;
        while (e) {
            if (e & 1) {
                f32x2 nr = qr * prr - qi * pri;
                qi = qr * pri + qi * prr;
                qr = nr;
            }
            f32x2 nr = prr * prr - pri * pri;
            pri = 2.f * prr * pri;
            prr = nr;
            e >>= 1;
        }
        f32x2 nr = zr * qr - zi * qi;
        ziB = zr * qi + zi * qr;
        zrB = nr;
    }

    float* q0 = &w3[0][wid * 368 + lane];
    float* q1 = &w3[1][wid * 368 + lane];
    float* q2 = &w3[2][wid * 368 + lane];

    #pragma unroll 1
    for (int j = 0; j < 150; j += 3) {
        // values for macro-steps j, j+1, j+2 on both streams
        float vA0 = zi.x + zi.y;
        { f32x2 nr = zr * Rr - zi * Ri; zi = zr * Ri + zi * Rr; zr = nr; }
        float vA1 = zi.x + zi.y;
        { f32x2 nr = zr * Rr - zi * Ri; zi = zr * Ri + zi * Rr; zr = nr; }
        float vA2 = zi.x + zi.y;
        { f32x2 nr = zr * Rr - zi * Ri; zi = zr * Ri + zi * Rr; zr = nr; }
        float vB0 = ziB.x + ziB.y;
        { f32x2 nr = zrB * Rr - ziB * Ri; ziB = zrB * Ri + ziB * Rr; zrB = nr; }
        float vB1 = ziB.x + ziB.y;
        { f32x2 nr = zrB * Rr - ziB * Ri; ziB = zrB * Ri + ziB * Rr; zrB = nr; }
        float vB2 = ziB.x + ziB.y;
        { f32x2 nr = zrB * Rr - ziB * Ri; ziB = zrB * Ri + ziB * Rr; zrB = nr; }

        // all 6 reads issue together -> single lgkm wait per group
        const float a0 = q0[j],     b0 = q0[j + 150];
        const float a1 = q1[j + 1], b1 = q1[j + 151];
        const float a2 = q2[j + 2], b2 = q2[j + 152];
        q0[j]       = a0 + vA0;  q0[j + 150] = b0 + vB0;
        q1[j + 1]   = a1 + vA1;  q1[j + 151] = b1 + vB1;
        q2[j + 2]   = a2 + vA2;  q2[j + 152] = b2 + vB2;
        __asm__ volatile("" ::: "memory");   // pin group order (cross-lane RAW, dist 3)
    }

    __syncthreads();
    // merge 3 parities x 4 wave windows + masked global flush
    for (int i = tid; i < 555; i += 256) {
        float sum = 0.f;
        #pragma unroll
        for (int w = 0; w < 4; ++w) {
            const int idx = i - (w << 6);
            if (idx >= 0 && idx < 363) {
                const int o = w * 368 + idx;
                sum += w3[0][o] + w3[1][o] + w3[2][o];
            }
        }
        const int pos = s0 + i;
        if (pos < SEQ) {
            (void)__hip_atomic_fetch_add(&kin[(size_t)imu * SEQ + pos], sum,
                                         __ATOMIC_RELAXED, __HIP_MEMORY_SCOPE_AGENT);
        }
    }
}

// ---------------- 4. acc/gyro base & std outputs (split-K combine) ----------------
__global__ __launch_bounds__(256) void tail_kernel(const float* __restrict__ ptA,
                                                   const float* __restrict__ ptB,
                                                   float* __restrict__ out) {
    const int i4 = blockIdx.x * 256 + threadIdx.x;   // float4 index, region = PLANE float4s
    if (i4 >= PLANE) return;
    const float4 a = ((const float4*)(ptA + (size_t)8 * PLANE))[i4];
    const float4 b = ((const float4*)(ptB + (size_t)8 * PLANE))[i4];
    float4 v;
    v.x = a.x + b.x; v.y = a.y + b.y; v.z = a.z + b.z; v.w = a.w + b.w;
    const int q = (int)(((size_t)i4 * 4) / PLANE);   // plane 0..3 (= noise 8..11)
    if (q & 1) {
        v.x = softplus_f(v.x); v.y = softplus_f(v.y);
        v.z = softplus_f(v.z); v.w = softplus_f(v.w);
    }
    ((float4*)(out + (size_t)PLANE))[i4] = v;
}

extern "C" void kernel_launch(void* const* d_in, const int* in_sizes, int n_in,
                              void* d_out, int out_size, void* d_ws, size_t ws_size,
                              hipStream_t stream) {
    const float* hs    = (const float*)d_in[0];
    const float* gamma = (const float*)d_in[1];
    const float* beta  = (const float*)d_in[2];
    const float* W     = (const float*)d_in[3];
    const float* b     = (const float*)d_in[4];
    float* out = (float*)d_out;

    short* A2f = (short*)d_ws;                        // 16.78 MB
    short* Btf = A2f + A2F_SHORTS;                    //  3.67 MB
    float* ptA = (float*)(Btf + BTF_SHORTS);          // 14.16 MB (split-K half 0 + bias)
    float* ptB = ptA + (size_t)12 * PLANE;            // 14.16 MB (split-K half 1)

    hipMemsetAsync(out, 0, (size_t)PLANE * sizeof(float), stream);

    ln_kernel<<<SEQ / 16, 512, 0, stream>>>(hs, gamma, beta, A2f);
    wprep_kernel<<<dim3(DM / 32, NJ / 32), 256, 0, stream>>>(W, Btf);
    gemm_kernel<<<448, 256, 0, stream>>>(A2f, Btf, b, ptA, ptB);
    spring_kernel<<<dim3(SEQ / 256, NIMU), 256, 0, stream>>>(ptA, ptB, out);
    tail_kernel<<<(PLANE + 255) / 256, 256, 0, stream>>>(ptA, ptB, out);
}

// Round 7
// 138.687 us; speedup vs baseline: 1.0860x; 1.0383x over previous
//
#include <hip/hip_runtime.h>
#include <hip/hip_bf16.h>
#include <math.h>

// Problem constants
#define SEQ 4096
#define DM  1024
#define NIMU 72
#define NNOISE 12
#define NJ (NIMU*NNOISE)     // 864
#define TSTEPS 300
#define PLANE (NIMU*SEQ)     // 294912

// R14 fragment-linear layouts (32x32x16 bf16 MFMA granules):
//   granule(tile, ch) = 512 shorts (1KB); lane l holds 8 shorts at +l*8:
//     row/col = l&31, k = ch*16 + (l>>5)*8 + 0..7
//   ch 0..63 = hi half (k 0..1023), ch 64..127 = lo half.
// A2f : 128 s_tiles x 128 ch x 512 shorts = 16.78 MB
// Btf : 28  j_tiles x 128 ch x 512 shorts =  3.67 MB (tile 27 = pad, never written)
// ptA/ptB : 12 x PLANE f32 split-K partials (14.16 MB each)
#define A2F_SHORTS ((size_t)128 * 128 * 512)
#define BTF_SHORTS ((size_t)28 * 128 * 512)

typedef __attribute__((ext_vector_type(8))) short bf16x8;
typedef __attribute__((ext_vector_type(16))) float f32x16;
typedef __attribute__((ext_vector_type(4))) float f32x4;
typedef __attribute__((ext_vector_type(2))) float f32x2;

__device__ __forceinline__ float softplus_f(float x) {
    return fmaxf(x, 0.f) + log1pf(expf(-fabsf(x)));
}

// round-to-nearest-even bf16 split: x ~= hi + lo with |err| ~ 2^-16 * |x|
__device__ __forceinline__ void split_bf16(float x, short& hi, short& lo) {
    unsigned b = __float_as_uint(x);
    unsigned h = (b + 0x7FFFu + ((b >> 16) & 1u)) >> 16;
    float hf = __uint_as_float(h << 16);
    float r = x - hf;
    unsigned b2 = __float_as_uint(r);
    unsigned l2 = (b2 + 0x7FFFu + ((b2 >> 16) & 1u)) >> 16;
    hi = (short)h;
    lo = (short)l2;
}

// async global->LDS, 16B per lane: dst = wave-uniform LDS base (+lane*16 by HW),
// src = per-lane global address.
__device__ __forceinline__ void gload_lds16(const void* g, void* l) {
    __builtin_amdgcn_global_load_lds(
        (const __attribute__((address_space(1))) unsigned int*)g,
        (__attribute__((address_space(3))) unsigned int*)l,
        16, 0, 0);
}

// ---------------- 1. LayerNorm -> A2f (32-row granules, bf16 hi|lo) ----------------
__global__ __launch_bounds__(512) void ln_kernel(const float* __restrict__ x,
                                                 const float* __restrict__ gamma,
                                                 const float* __restrict__ beta,
                                                 short* __restrict__ A2f) {
    const int tid = threadIdx.x;
    const int row = blockIdx.x * 16 + (tid >> 5);
    const int c   = tid & 31;
    const float4* xr = (const float4*)(x + (size_t)row * DM);

    float s = 0.f, sq = 0.f;
    #pragma unroll
    for (int i = 0; i < 8; ++i) {
        float4 v = xr[c + 32 * i];
        s  += v.x + v.y + v.z + v.w;
        sq += v.x*v.x + v.y*v.y + v.z*v.z + v.w*v.w;
    }
    #pragma unroll
    for (int off = 1; off < 32; off <<= 1) {     // 32-lane row groups within wave
        s  += __shfl_xor(s, off);
        sq += __shfl_xor(sq, off);
    }
    const float mean = s * (1.f / DM);
    const float var  = sq * (1.f / DM) - mean * mean;
    const float rstd = rsqrtf(fmaxf(var, 0.f) + 1e-5f);

    const int s_tile = row >> 5, r = row & 31;
    #pragma unroll
    for (int i = 0; i < 8; ++i) {
        const int c4 = c + 32 * i;               // float4 column 0..255, k = 4*c4..+3
        float4 v  = xr[c4];
        float4 gm = ((const float4*)gamma)[c4];
        float4 bt = ((const float4*)beta)[c4];
        float o[4];
        o[0] = (v.x - mean) * rstd * gm.x + bt.x;
        o[1] = (v.y - mean) * rstd * gm.y + bt.y;
        o[2] = (v.z - mean) * rstd * gm.z + bt.z;
        o[3] = (v.w - mean) * rstd * gm.w + bt.w;
        short4 hv, lv;
        split_bf16(o[0], hv.x, lv.x);
        split_bf16(o[1], hv.y, lv.y);
        split_bf16(o[2], hv.z, lv.z);
        split_bf16(o[3], hv.w, lv.w);
        const int ch = c4 >> 2;                  // 16-k chunk
        const int g  = (c4 >> 1) & 1;            // 8-k group within chunk
        const int o4 = (c4 & 1) * 4;             // short offset within group
        const size_t base = ((size_t)s_tile * 128 + ch) * 512 + (g * 32 + r) * 8 + o4;
        *(short4*)(A2f + base)                    = hv;   // hi: ch
        *(short4*)(A2f + base + (size_t)64 * 512) = lv;   // lo: ch+64
    }
}

// ---------------- 2a. W -> Btf (transpose + split, 32-col granules) ----------------
__global__ __launch_bounds__(256) void wprep_kernel(const float* __restrict__ W,
                                                    short* __restrict__ Btf) {
    __shared__ float T[32][33];
    const int k0 = blockIdx.x * 32, j0 = blockIdx.y * 32;
    const int t = threadIdx.x;
    {
        const int r = t >> 3, c4 = (t & 7) * 4;
        float4 v = *(const float4*)(W + (size_t)(k0 + r) * NJ + j0 + c4);
        T[r][c4 + 0] = v.x; T[r][c4 + 1] = v.y; T[r][c4 + 2] = v.z; T[r][c4 + 3] = v.w;
    }
    __syncthreads();
    if (t < 128) {
        const int q = t >> 6;                    // which 16-k chunk of the 32
        const int l = t & 63;
        const int n = l & 31, g = l >> 5;
        const int jt = blockIdx.y;               // j_tile (32 cols)
        const int ch = blockIdx.x * 2 + q;
        bf16x8 hv, lv;
        #pragma unroll
        for (int o = 0; o < 8; ++o) {
            short h, lo_;
            split_bf16(T[q * 16 + g * 8 + o][n], h, lo_);
            hv[o] = h; lv[o] = lo_;
        }
        short* dh = Btf + ((size_t)jt * 128 + ch) * 512 + l * 8;
        *(bf16x8*)dh = hv;
        *(bf16x8*)(dh + (size_t)64 * 512) = lv;  // lo chunk = ch+64
    }
}

// ---------------- 2b. LDS-staged MFMA GEMM, 32x32x16, split-K=2 ----------------
// R14 post-mortem: ~31us, still vmem-path-bound -- each wave fetched operands
// privately (32 KB/block/k-step through TA/TCP for 16 KB distinct).
// R15 (m97 pattern, guide §5): stage the block's 16 distinct granules ONCE per
// k-step into LDS via global_load_lds width=16 (no VGPR round-trip; vmem traffic
// halves to 229 MB), all 4 waves ds_read_b128 fragments from LDS (separate pipe).
// Double-buffered (64 KB LDS; 2 blocks/CU = 128/160 KB), 2-phase loop: issue
// next-tile stage -> compute current -> __syncthreads() (drains vmcnt before
// s_barrier). BK=32k (2 ch/iter) -> 16 iters. Stage split: wave w stages ch
// (w>>1), A-side if !(w&1), 8 granules each. Epilogue/split-K unchanged.
__global__ __launch_bounds__(256, 2) void gemm_kernel(const short* __restrict__ A2f,
                                                      const short* __restrict__ Btf,
                                                      const float* __restrict__ bias,
                                                      float* __restrict__ ptA,
                                                      float* __restrict__ ptB) {
    // lds[buf][G][lane]: G = ch_local*16 + (g<8 ? A granule g : B granule g-8+8)
    //   A granule g: mt = g>>1, part = g&1;  B granule: jt = (g-8)>>1, part.
    __shared__ bf16x8 lds[2][32][64];            // 64 KB

    const int bid = blockIdx.x;
    const int c = bid & 7, u = bid >> 3;         // c = XCD, u 0..55
    const int kh = u / 28, v = u - kh * 28;      // kh = K-half
    const int bxi = v / 7, by = v - bxi * 7;     // bxi 0..3, by 0..6
    const int bx = c * 4 + bxi;                  // 0..31
    const int l = threadIdx.x & 63, w = threadIdx.x >> 6;
    const int bx4 = bx * 4, by4 = by * 4;        // block tile bases (32-granule units)
    const int mt0 = bx4 + (w & 1) * 2;           // wave's m-tile base
    const int jt0 = by4 + (w >> 1) * 2;          // wave's j-tile base
    const int ch0 = kh * 32;                     // 16-k chunks; half = 32 chunks

    // staging role (wave-uniform)
    const int schl = w >> 1;                     // which ch_local this wave stages
    const bool sA  = (w & 1) == 0;               // A-side or B-side

    auto stage = [&](int buf, int it) {
        const int ch = ch0 + it * 2 + schl;
        #pragma unroll
        for (int i = 0; i < 8; ++i) {
            const int tt = i >> 1, part = i & 1;
            const short* src = sA
                ? A2f + ((size_t)(bx4 + tt) * 128 + ch + part * 64) * 512 + l * 8
                : Btf + ((size_t)(by4 + tt) * 128 + ch + part * 64) * 512 + l * 8;
            gload_lds16(src, &lds[buf][schl * 16 + (sA ? 0 : 8) + i][0]);
        }
    };

    f32x16 acc[2][2] = {};
    const int wa = (w & 1) * 2;                  // wave's A granule-pair base (tile units)
    const int wb = (w >> 1) * 2;                 // wave's B granule-pair base

    stage(0, 0);
    __syncthreads();

    for (int it = 0; it < 16; ++it) {
        const int cur = it & 1;
        if (it + 1 < 16) stage(cur ^ 1, it + 1);
        #pragma unroll
        for (int chl = 0; chl < 2; ++chl) {
            const int gb = chl * 16;
            bf16x8 a0h = lds[cur][gb + (wa + 0) * 2 + 0][l];
            bf16x8 a0l = lds[cur][gb + (wa + 0) * 2 + 1][l];
            bf16x8 a1h = lds[cur][gb + (wa + 1) * 2 + 0][l];
            bf16x8 a1l = lds[cur][gb + (wa + 1) * 2 + 1][l];
            bf16x8 b0h = lds[cur][gb + 8 + (wb + 0) * 2 + 0][l];
            bf16x8 b0l = lds[cur][gb + 8 + (wb + 0) * 2 + 1][l];
            bf16x8 b1h = lds[cur][gb + 8 + (wb + 1) * 2 + 0][l];
            bf16x8 b1l = lds[cur][gb + 8 + (wb + 1) * 2 + 1][l];
            acc[0][0] = __builtin_amdgcn_mfma_f32_32x32x16_bf16(a0h, b0h, acc[0][0], 0, 0, 0);
            acc[0][1] = __builtin_amdgcn_mfma_f32_32x32x16_bf16(a0h, b1h, acc[0][1], 0, 0, 0);
            acc[1][0] = __builtin_amdgcn_mfma_f32_32x32x16_bf16(a1h, b0h, acc[1][0], 0, 0, 0);
            acc[1][1] = __builtin_amdgcn_mfma_f32_32x32x16_bf16(a1h, b1h, acc[1][1], 0, 0, 0);
            acc[0][0] = __builtin_amdgcn_mfma_f32_32x32x16_bf16(a0h, b0l, acc[0][0], 0, 0, 0);
            acc[0][1] = __builtin_amdgcn_mfma_f32_32x32x16_bf16(a0h, b1l, acc[0][1], 0, 0, 0);
            acc[1][0] = __builtin_amdgcn_mfma_f32_32x32x16_bf16(a1h, b0l, acc[1][0], 0, 0, 0);
            acc[1][1] = __builtin_amdgcn_mfma_f32_32x32x16_bf16(a1h, b1l, acc[1][1], 0, 0, 0);
            acc[0][0] = __builtin_amdgcn_mfma_f32_32x32x16_bf16(a0l, b0h, acc[0][0], 0, 0, 0);
            acc[0][1] = __builtin_amdgcn_mfma_f32_32x32x16_bf16(a0l, b1h, acc[0][1], 0, 0, 0);
            acc[1][0] = __builtin_amdgcn_mfma_f32_32x32x16_bf16(a1l, b0h, acc[1][0], 0, 0, 0);
            acc[1][1] = __builtin_amdgcn_mfma_f32_32x32x16_bf16(a1l, b1h, acc[1][1], 0, 0, 0);
        }
        __syncthreads();                         // drains vmcnt (stage) + lgkm, all waves
    }

    // epilogue: 32x32 C/D layout col=lane&31 (j), row=(reg&3)+8*(reg>>2)+4*(lane>>5)
    float* ptH = kh ? ptB : ptA;
    const int jn = l & 31, hi5 = l >> 5;
    #pragma unroll
    for (int ni = 0; ni < 2; ++ni) {
        const int jt = jt0 + ni;
        if (jt < 27) {                            // tile 27 = pad, fully masked
            const int j = jt * 32 + jn;
            const float bj = (kh == 0) ? bias[j] : 0.f;
            #pragma unroll
            for (int mi = 0; mi < 2; ++mi) {
                #pragma unroll
                for (int q = 0; q < 4; ++q) {     // reg quad q -> rows q*8+hi5*4+0..3
                    f32x4 o;
                    o[0] = acc[mi][ni][q * 4 + 0] + bj;
                    o[1] = acc[mi][ni][q * 4 + 1] + bj;
                    o[2] = acc[mi][ni][q * 4 + 2] + bj;
                    o[3] = acc[mi][ni][q * 4 + 3] + bj;
                    const int s = (mt0 + mi) * 32 + q * 8 + hi5 * 4;
                    *(f32x4*)(ptH + (size_t)j * SEQ + s) = o;
                }
            }
        }
    }
}

// ---------------- 3. Spring recurrence + wave-private LDS-window scatter ----------------
// R11 structure unchanged (3-parity buffers, 1 lgkm wait per 3 macro-steps).
__global__ __launch_bounds__(256) void spring_kernel(const float* __restrict__ ptA,
                                                     const float* __restrict__ ptB,
                                                     float* __restrict__ kin) {
    __shared__ float w3[3][4 * 368];           // 363 used per wave per parity
    const int tid  = threadIdx.x;
    const int lane = tid & 63;
    const int wid  = tid >> 6;
    const int s0   = blockIdx.x * 256;
    const int imu  = blockIdx.y;
    const int s    = s0 + (wid << 6) + lane;

    // zero own windows (wave-private: no barrier needed before main loop)
    #pragma unroll
    for (int b = 0; b < 3; ++b)
        #pragma unroll
        for (int i = 0; i < 6; ++i) {
            const int idx = lane + i * 64;
            if (idx < 363) w3[b][wid * 368 + idx] = 0.f;
        }

    const int base = imu * SEQ + s;
    const float p0  = ptA[(size_t)0 * PLANE + base] + ptB[(size_t)0 * PLANE + base];
    const float p1  = ptA[(size_t)1 * PLANE + base] + ptB[(size_t)1 * PLANE + base];
    const float p2  = ptA[(size_t)2 * PLANE + base] + ptB[(size_t)2 * PLANE + base];
    const float p3  = ptA[(size_t)3 * PLANE + base] + ptB[(size_t)3 * PLANE + base];
    const float c1  = ptA[(size_t)4 * PLANE + base] + ptB[(size_t)4 * PLANE + base];
    const float c2  = ptA[(size_t)5 * PLANE + base] + ptB[(size_t)5 * PLANE + base];
    const float ph1 = ptA[(size_t)6 * PLANE + base] + ptB[(size_t)6 * PLANE + base];
    const float ph2 = ptA[(size_t)7 * PLANE + base] + ptB[(size_t)7 * PLANE + base];

    float dd = softplus_f(p1);
    float kk = dd * dd * 0.25f + softplus_f(p0);
    float om1 = 0.5f * sqrtf(fmaxf(4.f * kk - dd * dd, 0.f));
    float dt = softplus_f(p3);
    float kt = dt * dt * 0.25f + softplus_f(p2);
    float om2 = 0.5f * sqrtf(fmaxf(4.f * kt - dt * dt, 0.f));
    float e1 = expf(-0.5f * dd), e2 = expf(-0.5f * dt);
    float sn, cs, sn2, cs2;
    sincosf(om1, &sn, &cs);
    sincosf(om2, &sn2, &cs2);
    f32x2 Rr = {e1 * cs, e2 * cs2};          // per-step rotation (packed: osc1, osc2)
    f32x2 Ri = {e1 * sn, e2 * sn2};
    sincosf(ph1, &sn, &cs);
    sincosf(ph2, &sn2, &cs2);
    f32x2 zr = {c1 * cs, c2 * cs2};          // stream A state (t = 0)
    f32x2 zi = {c1 * sn, c2 * sn2};

    // stream B state: z * R^150 (exp-by-squaring)
    f32x2 zrB, ziB;
    {
        f32x2 prr = Rr, pri = Ri;
        f32x2 qr = {1.f, 1.f}, qi = {0.f, 0.f};
        int e = 150;
        while (e) {
            if (e & 1) {
                f32x2 nr = qr * prr - qi * pri;
                qi = qr * pri + qi * prr;
                qr = nr;
            }
            f32x2 nr = prr * prr - pri * pri;
            pri = 2.f * prr * pri;
            prr = nr;
            e >>= 1;
        }
        f32x2 nr = zr * qr - zi * qi;
        ziB = zr * qi + zi * qr;
        zrB = nr;
    }

    float* q0 = &w3[0][wid * 368 + lane];
    float* q1 = &w3[1][wid * 368 + lane];
    float* q2 = &w3[2][wid * 368 + lane];

    #pragma unroll 1
    for (int j = 0; j < 150; j += 3) {
        // values for macro-steps j, j+1, j+2 on both streams
        float vA0 = zi.x + zi.y;
        { f32x2 nr = zr * Rr - zi * Ri; zi = zr * Ri + zi * Rr; zr = nr; }
        float vA1 = zi.x + zi.y;
        { f32x2 nr = zr * Rr - zi * Ri; zi = zr * Ri + zi * Rr; zr = nr; }
        float vA2 = zi.x + zi.y;
        { f32x2 nr = zr * Rr - zi * Ri; zi = zr * Ri + zi * Rr; zr = nr; }
        float vB0 = ziB.x + ziB.y;
        { f32x2 nr = zrB * Rr - ziB * Ri; ziB = zrB * Ri + ziB * Rr; zrB = nr; }
        float vB1 = ziB.x + ziB.y;
        { f32x2 nr = zrB * Rr - ziB * Ri; ziB = zrB * Ri + ziB * Rr; zrB = nr; }
        float vB2 = ziB.x + ziB.y;
        { f32x2 nr = zrB * Rr - ziB * Ri; ziB = zrB * Ri + ziB * Rr; zrB = nr; }

        // all 6 reads issue together -> single lgkm wait per group
        const float a0 = q0[j],     b0 = q0[j + 150];
        const float a1 = q1[j + 1], b1 = q1[j + 151];
        const float a2 = q2[j + 2], b2 = q2[j + 152];
        q0[j]       = a0 + vA0;  q0[j + 150] = b0 + vB0;
        q1[j + 1]   = a1 + vA1;  q1[j + 151] = b1 + vB1;
        q2[j + 2]   = a2 + vA2;  q2[j + 152] = b2 + vB2;
        __asm__ volatile("" ::: "memory");   // pin group order (cross-lane RAW, dist 3)
    }

    __syncthreads();
    // merge 3 parities x 4 wave windows + masked global flush
    for (int i = tid; i < 555; i += 256) {
        float sum = 0.f;
        #pragma unroll
        for (int w = 0; w < 4; ++w) {
            const int idx = i - (w << 6);
            if (idx >= 0 && idx < 363) {
                const int o = w * 368 + idx;
                sum += w3[0][o] + w3[1][o] + w3[2][o];
            }
        }
        const int pos = s0 + i;
        if (pos < SEQ) {
            (void)__hip_atomic_fetch_add(&kin[(size_t)imu * SEQ + pos], sum,
                                         __ATOMIC_RELAXED, __HIP_MEMORY_SCOPE_AGENT);
        }
    }
}

// ---------------- 4. acc/gyro base & std outputs (split-K combine) ----------------
__global__ __launch_bounds__(256) void tail_kernel(const float* __restrict__ ptA,
                                                   const float* __restrict__ ptB,
                                                   float* __restrict__ out) {
    const int i4 = blockIdx.x * 256 + threadIdx.x;   // float4 index, region = PLANE float4s
    if (i4 >= PLANE) return;
    const float4 a = ((const float4*)(ptA + (size_t)8 * PLANE))[i4];
    const float4 b = ((const float4*)(ptB + (size_t)8 * PLANE))[i4];
    float4 v;
    v.x = a.x + b.x; v.y = a.y + b.y; v.z = a.z + b.z; v.w = a.w + b.w;
    const int q = (int)(((size_t)i4 * 4) / PLANE);   // plane 0..3 (= noise 8..11)
    if (q & 1) {
        v.x = softplus_f(v.x); v.y = softplus_f(v.y);
        v.z = softplus_f(v.z); v.w = softplus_f(v.w);
    }
    ((float4*)(out + (size_t)PLANE))[i4] = v;
}

extern "C" void kernel_launch(void* const* d_in, const int* in_sizes, int n_in,
                              void* d_out, int out_size, void* d_ws, size_t ws_size,
                              hipStream_t stream) {
    const float* hs    = (const float*)d_in[0];
    const float* gamma = (const float*)d_in[1];
    const float* beta  = (const float*)d_in[2];
    const float* W     = (const float*)d_in[3];
    const float* b     = (const float*)d_in[4];
    float* out = (float*)d_out;

    short* A2f = (short*)d_ws;                        // 16.78 MB
    short* Btf = A2f + A2F_SHORTS;                    //  3.67 MB
    float* ptA = (float*)(Btf + BTF_SHORTS);          // 14.16 MB (split-K half 0 + bias)
    float* ptB = ptA + (size_t)12 * PLANE;            // 14.16 MB (split-K half 1)

    hipMemsetAsync(out, 0, (size_t)PLANE * sizeof(float), stream);

    ln_kernel<<<SEQ / 16, 512, 0, stream>>>(hs, gamma, beta, A2f);
    wprep_kernel<<<dim3(DM / 32, NJ / 32), 256, 0, stream>>>(W, Btf);
    gemm_kernel<<<448, 256, 0, stream>>>(A2f, Btf, b, ptA, ptB);
    spring_kernel<<<dim3(SEQ / 256, NIMU), 256, 0, stream>>>(ptA, ptB, out);
    tail_kernel<<<(PLANE + 255) / 256, 256, 0, stream>>>(ptA, ptB, out);
}